// Round 5
// baseline (273.001 us; speedup 1.0000x reference)
//
#include <hip/hip_runtime.h>

#define NCAND 40
#define NC2   1600
#define NP    256
#define NB    256
#define TPB   1024

// Grid barrier for exactly-co-resident grids (256 blocks x 1 CU each).
// Monotone counter: call with target=NB, then 2*NB. Counter is zeroed by a
// hipMemsetAsync at the head of every launch, so replays are deterministic.
__device__ __forceinline__ void gbar(unsigned* cnt, unsigned target) {
    __syncthreads();
    __threadfence();                                   // release: publish stores
    if (threadIdx.x == 0) {
        __hip_atomic_fetch_add(cnt, 1u, __ATOMIC_RELEASE, __HIP_MEMORY_SCOPE_AGENT);
        while (__hip_atomic_load(cnt, __ATOMIC_ACQUIRE, __HIP_MEMORY_SCOPE_AGENT) < target) {
            __builtin_amdgcn_s_sleep(1);
        }
    }
    __syncthreads();
    __threadfence();                                   // acquire: drop stale lines
}

__global__ __launch_bounds__(TPB, 1) void k_fused(
        const float* __restrict__ feat0, const float* __restrict__ feat1,
        const float* __restrict__ feat2, const float* __restrict__ feat3,
        const int* __restrict__ loc,
        float* __restrict__ dist, int* __restrict__ hw,
        unsigned* __restrict__ cnt, float* __restrict__ out) {
    __shared__ float sh[NC2];          // phase A: sample patch (768); phase B: dist stage
    __shared__ double red[16];

    const int tid  = threadIdx.x;
    const int wid  = tid >> 6;
    const int lane = tid & 63;
    const int b    = blockIdx.x;
    const int lh = loc[0], lw = loc[1];

    // ================= Phase A: candidate distances (numpy-f32-exact) =========
    for (int t = tid; t < 768; t += TPB) {
        int c = t >> 8, rem = t & 255, a = rem >> 4, bb = rem & 15;
        sh[t] = feat0[c * 65536 + (lh - 8 + a) * 256 + (lw - 8 + bb)];
    }
    __syncthreads();

    const int cand = wid * NB + b;     // unique wave id 0..4095; <1600 active
    if (cand < NC2) {
        const int i = cand / NCAND, j = cand % NCAND;
        const int base_h = lh - 28 + i, base_w = lw - 28 + j;
        int c = lane >> 4; if (c > 2) c = 0;            // lanes 48..63 duplicate c=0
        const int h = (lane >> 3) & 1, u = lane & 7;
        const float* fp = feat0 + c * 65536;
        const float* sc = sh + c * 256;
        float r = 0.0f;
#pragma unroll
        for (int k = 0; k < 16; ++k) {
            const int idx = h * 128 + k * 8 + u;        // flat a*16+b in the patch
            const int a = idx >> 4, bb = idx & 15;
            float v = fp[(base_h + a) * 256 + base_w + bb];
            float d = __fsub_rn(v, sc[idx]);
            float sq = __fmul_rn(d, d);
            r = (k == 0) ? sq : __fadd_rn(r, sq);
        }
        // numpy pairwise tree via bit-exact butterfly, then sequential channels
        r = __fadd_rn(r, __shfl_xor(r, 1, 64));
        r = __fadd_rn(r, __shfl_xor(r, 2, 64));
        r = __fadd_rn(r, __shfl_xor(r, 4, 64));
        r = __fadd_rn(r, __shfl_xor(r, 8, 64));
        float p1 = __shfl(r, 16, 64);
        float p2 = __shfl(r, 32, 64);
        float tot = __fadd_rn(__fadd_rn(r, p1), p2);
        if (lane == 0)
            __hip_atomic_store(&dist[cand], __fsqrt_rn(tot),
                               __ATOMIC_RELAXED, __HIP_MEMORY_SCOPE_AGENT);
    }

    gbar(cnt, NB);

    // ================= Phase B: exact rank selection ==========================
    for (int k = tid; k < NC2; k += TPB)
        sh[k] = __hip_atomic_load(&dist[k], __ATOMIC_RELAXED, __HIP_MEMORY_SCOPE_AGENT);
    __syncthreads();

    if (cand < NC2) {
        const int t = cand;
        const float dt = sh[t];
        int rank = 0;
#pragma unroll
        for (int m = 0; m < NC2 / 64; ++m) {
            const int k = lane + (m << 6);
            const float dk = sh[k];
            rank += (dk < dt || (dk == dt && k < t)) ? 1 : 0;
        }
        rank += __shfl_xor(rank, 1, 64);
        rank += __shfl_xor(rank, 2, 64);
        rank += __shfl_xor(rank, 4, 64);
        rank += __shfl_xor(rank, 8, 64);
        rank += __shfl_xor(rank, 16, 64);
        rank += __shfl_xor(rank, 32, 64);

        if (lane == 0 && rank < NP) {
            const int h = lh - 20 + t / NCAND;
            const int w = lw - 20 + t % NCAND;
            __hip_atomic_store(&hw[rank * 2],     h, __ATOMIC_RELAXED, __HIP_MEMORY_SCOPE_AGENT);
            __hip_atomic_store(&hw[rank * 2 + 1], w, __ATOMIC_RELAXED, __HIP_MEMORY_SCOPE_AGENT);
            float* out_ids = out + 768 + 65536 + 131072 + 262144;
            out_ids[rank * 2]     = (float)h;
            out_ids[rank * 2 + 1] = (float)w;
        }
    }

    gbar(cnt, 2 * NB);

    // ================= Phase C: gather + L2-normalize =========================
    // block = patch r; 256-thread quarter q = feature q.
    const int q  = tid >> 8;
    const int lt = tid & 255;
    const int r  = b;

    const float* src; int C, H; long off;
    if (q == 0)      { src = feat0; C = 3;    H = 256; off = 0; }
    else if (q == 1) { src = feat1; C = 256;  H = 256; off = 768; }
    else if (q == 2) { src = feat2; C = 512;  H = 128; off = 768 + 65536; }
    else             { src = feat3; C = 1024; H = 64;  off = 768 + 65536 + 131072; }
    const int W = H;

    const int h = __hip_atomic_load(&hw[r * 2],     __ATOMIC_RELAXED, __HIP_MEMORY_SCOPE_AGENT);
    const int w = __hip_atomic_load(&hw[r * 2 + 1], __ATOMIC_RELAXED, __HIP_MEMORY_SCOPE_AGENT);
    const int hh = (h * H) / 256, ww = (w * H) / 256;
    const long base = (long)hh * W + ww;
    const long HW = (long)H * W;

    // statically-indexed gather (avoid scratch), same sequential fma order as before
    float x0 = 0.f, x1 = 0.f, x2 = 0.f, x3 = 0.f;
    double acc = 0.0;
    {
        int c = lt;
        if (c < C) { x0 = src[(long)c * HW + base]; acc = fma((double)x0, (double)x0, acc); }
        c += 256;
        if (c < C) { x1 = src[(long)c * HW + base]; acc = fma((double)x1, (double)x1, acc); }
        c += 256;
        if (c < C) { x2 = src[(long)c * HW + base]; acc = fma((double)x2, (double)x2, acc); }
        c += 256;
        if (c < C) { x3 = src[(long)c * HW + base]; acc = fma((double)x3, (double)x3, acc); }
    }
    for (int o = 32; o > 0; o >>= 1) acc += __shfl_down(acc, o, 64);
    if (lane == 0) red[wid] = acc;
    __syncthreads();
    const double total = red[q * 4] + red[q * 4 + 1] + red[q * 4 + 2] + red[q * 4 + 3];
    const float scale = (float)(1.0 / (sqrt(total) + 1e-7));
    {
        int c = lt;
        if (c < C) out[off + (long)r * C + c] = x0 * scale;
        c += 256;
        if (c < C) out[off + (long)r * C + c] = x1 * scale;
        c += 256;
        if (c < C) out[off + (long)r * C + c] = x2 * scale;
        c += 256;
        if (c < C) out[off + (long)r * C + c] = x3 * scale;
    }
}

extern "C" void kernel_launch(void* const* d_in, const int* in_sizes, int n_in,
                              void* d_out, int out_size, void* d_ws, size_t ws_size,
                              hipStream_t stream) {
    const float* feat0 = (const float*)d_in[0];
    const float* feat1 = (const float*)d_in[1];
    const float* feat2 = (const float*)d_in[2];
    const float* feat3 = (const float*)d_in[3];
    const int*   loc   = (const int*)d_in[4];
    float* out = (float*)d_out;

    // ws layout: dist[1600] floats @0; hw[512] ints @6400; cnt (unsigned) @8448
    float*    dist = (float*)d_ws;
    int*      hw   = (int*)((char*)d_ws + NC2 * sizeof(float));
    unsigned* cnt  = (unsigned*)((char*)d_ws + NC2 * sizeof(float) + 2 * NP * sizeof(int));

    hipMemsetAsync(cnt, 0, sizeof(unsigned), stream);
    k_fused<<<NB, TPB, 0, stream>>>(feat0, feat1, feat2, feat3, loc, dist, hw, cnt, out);
}

// Round 6
// 18.908 us; speedup vs baseline: 14.4385x; 14.4385x over previous
//
#include <hip/hip_runtime.h>

#define NCAND 40
#define NC2   1600
#define NP    256

// ---------------- Kernel 1: candidate patch distances (float32, numpy-exact) ----
// Wave-per-candidate. Lane = c*16 + h*8 + u (lanes 0..47 active, 48..63 compute
// harmless duplicates). Each lane runs one 16-step sequential accumulator chain
// r[u]; the numpy pairwise tree ((r0+r1)+(r2+r3))+((r4+r5)+(r6+r7)) is realized
// bit-exactly by a shfl_xor butterfly (IEEE add commutes), xor8 merges halves,
// explicit shfl from lanes 16/32 gives the sequential channel sum (p0+p1)+p2.
// All ops via __f*_rn intrinsics to block fp-contract=fast.
// DO NOT change the arithmetic order here: patch_ids correctness depends on
// bit-exact replication of the numpy f32 reduction tree.
__global__ void k_dist(const float* __restrict__ feat0,
                       const int* __restrict__ loc,
                       float* __restrict__ dist) {
    __shared__ float smp[3 * 16 * 16];
    const int lh = loc[0], lw = loc[1];
    for (int t = threadIdx.x; t < 768; t += 256) {
        int c = t >> 8;
        int rem = t & 255;
        int a = rem >> 4;
        int b = rem & 15;
        smp[t] = feat0[c * 65536 + (lh - 8 + a) * 256 + (lw - 8 + b)];
    }
    __syncthreads();

    const int wid  = threadIdx.x >> 6;
    const int lane = threadIdx.x & 63;
    const int cand = blockIdx.x * 4 + wid;          // 400 blocks * 4 waves = 1600
    const int i = cand / NCAND;
    const int j = cand % NCAND;
    const int base_h = lh - 28 + i;
    const int base_w = lw - 28 + j;

    int c = lane >> 4;
    if (c > 2) c = 0;                               // lanes 48..63: duplicate c=0
    const int h = (lane >> 3) & 1;
    const int u = lane & 7;
    const float* fp = feat0 + c * 65536;
    const float* sc = smp + c * 256;

    float r = 0.0f;
#pragma unroll
    for (int k = 0; k < 16; ++k) {
        const int idx = h * 128 + k * 8 + u;        // flat a*16+b within the patch
        const int a = idx >> 4;
        const int b = idx & 15;
        float v = fp[(base_h + a) * 256 + base_w + b];
        float d = __fsub_rn(v, sc[idx]);
        float sq = __fmul_rn(d, d);
        r = (k == 0) ? sq : __fadd_rn(r, sq);
    }
    // pairwise tree over u (bit-exact butterfly), then halves (h bit)
    r = __fadd_rn(r, __shfl_xor(r, 1, 64));
    r = __fadd_rn(r, __shfl_xor(r, 2, 64));
    r = __fadd_rn(r, __shfl_xor(r, 4, 64));
    r = __fadd_rn(r, __shfl_xor(r, 8, 64));
    // sequential channel combine (p0+p1)+p2, valid on lane 0
    float p1 = __shfl(r, 16, 64);
    float p2 = __shfl(r, 32, 64);
    float tot = __fadd_rn(__fadd_rn(r, p1), p2);
    if (lane == 0) dist[cand] = __fsqrt_rn(tot);
}

// ---------------- Kernel 2: exact rank selection (top-256 ascending) --------
// Wave-per-candidate: wave t computes rank(t) = #{k : d[k]<d[t] || (d[k]==d[t]
// && k<t)} with lane l scanning k = l + 64*m (25 steps), then a shfl_xor
// integer reduce. Strict total order == top_k tie-breaking (lower index first).
__global__ void k_rank(const float* __restrict__ dist,
                       const int* __restrict__ loc,
                       int* __restrict__ hw,
                       float* __restrict__ out_ids) {
    __shared__ float ds[NC2];
    for (int k = threadIdx.x; k < NC2; k += 256) ds[k] = dist[k];
    __syncthreads();

    const int wid  = threadIdx.x >> 6;
    const int lane = threadIdx.x & 63;
    const int t = blockIdx.x * 4 + wid;             // 400 blocks * 4 waves = 1600
    const float dt = ds[t];
    int rank = 0;
#pragma unroll
    for (int m = 0; m < NC2 / 64; ++m) {
        const int k = lane + (m << 6);
        const float dk = ds[k];
        rank += (dk < dt || (dk == dt && k < t)) ? 1 : 0;
    }
    rank += __shfl_xor(rank, 1, 64);
    rank += __shfl_xor(rank, 2, 64);
    rank += __shfl_xor(rank, 4, 64);
    rank += __shfl_xor(rank, 8, 64);
    rank += __shfl_xor(rank, 16, 64);
    rank += __shfl_xor(rank, 32, 64);

    if (lane == 0 && rank < NP) {
        const int lh = loc[0], lw = loc[1];
        const int h = lh - 20 + t / NCAND;
        const int w = lw - 20 + t % NCAND;
        hw[rank * 2]     = h;
        hw[rank * 2 + 1] = w;
        out_ids[rank * 2]     = (float)h;
        out_ids[rank * 2 + 1] = (float)w;
    }
}

// ---------------- Kernel 3: gather + L2-normalize (f32 reduce) --------------
// Threshold for outputs 0-3 is a loose scalar (~1.84); reference norm is f32
// anyway, so f32 accumulate + sqrtf is accurate to ~1e-5 -- no fp64 needed.
__global__ void k_gather(const float* __restrict__ f0,
                         const float* __restrict__ f1,
                         const float* __restrict__ f2,
                         const float* __restrict__ f3,
                         const int* __restrict__ hw,
                         float* __restrict__ out) {
    const int r = blockIdx.x & 255;
    const int f = blockIdx.x >> 8;

    const float* src;
    int C, H;
    long off;
    if (f == 0)      { src = f0; C = 3;    H = 256; off = 0; }
    else if (f == 1) { src = f1; C = 256;  H = 256; off = 768; }
    else if (f == 2) { src = f2; C = 512;  H = 128; off = 768 + 65536; }
    else             { src = f3; C = 1024; H = 64;  off = 768 + 65536 + 131072; }
    const int W = H;

    const int h = hw[r * 2], w = hw[r * 2 + 1];
    const int hh = (h * H) / 256;
    const int ww = (w * H) / 256;
    const long base = (long)hh * W + ww;
    const long HW = (long)H * W;

    // statically-indexed gather (max 4 channels per thread at C=1024)
    float x0 = 0.f, x1 = 0.f, x2 = 0.f, x3 = 0.f;
    float acc = 0.f;
    {
        int c = threadIdx.x;
        if (c < C) { x0 = src[(long)c * HW + base]; acc = fmaf(x0, x0, acc); }
        c += 256;
        if (c < C) { x1 = src[(long)c * HW + base]; acc = fmaf(x1, x1, acc); }
        c += 256;
        if (c < C) { x2 = src[(long)c * HW + base]; acc = fmaf(x2, x2, acc); }
        c += 256;
        if (c < C) { x3 = src[(long)c * HW + base]; acc = fmaf(x3, x3, acc); }
    }

    for (int o = 32; o > 0; o >>= 1) acc += __shfl_down(acc, o, 64);
    __shared__ float red[4];
    const int lane = threadIdx.x & 63;
    const int wid  = threadIdx.x >> 6;
    if (lane == 0) red[wid] = acc;
    __syncthreads();
    const float total = red[0] + red[1] + red[2] + red[3];
    const float scale = 1.0f / (sqrtf(total) + 1e-7f);

    {
        int c = threadIdx.x;
        if (c < C) out[off + (long)r * C + c] = x0 * scale;
        c += 256;
        if (c < C) out[off + (long)r * C + c] = x1 * scale;
        c += 256;
        if (c < C) out[off + (long)r * C + c] = x2 * scale;
        c += 256;
        if (c < C) out[off + (long)r * C + c] = x3 * scale;
    }
}

extern "C" void kernel_launch(void* const* d_in, const int* in_sizes, int n_in,
                              void* d_out, int out_size, void* d_ws, size_t ws_size,
                              hipStream_t stream) {
    const float* feat0 = (const float*)d_in[0];
    const float* feat1 = (const float*)d_in[1];
    const float* feat2 = (const float*)d_in[2];
    const float* feat3 = (const float*)d_in[3];
    const int*   loc   = (const int*)d_in[4];
    float* out = (float*)d_out;

    float* dist = (float*)d_ws;                              // 1600 floats
    int* hw = (int*)((char*)d_ws + NC2 * sizeof(float));     // 512 ints

    float* out_ids = out + 768 + 65536 + 131072 + 262144;    // offset 459520

    k_dist<<<NC2 / 4, 256, 0, stream>>>(feat0, loc, dist);
    k_rank<<<NC2 / 4, 256, 0, stream>>>(dist, loc, hw, out_ids);
    k_gather<<<4 * NP, 256, 0, stream>>>(feat0, feat1, feat2, feat3, hw, out);
}